// Round 1
// baseline (633.487 us; speedup 1.0000x reference)
//
#include <hip/hip_runtime.h>
#include <hip/hip_bf16.h>
#include <math.h>

// GraphSAGE 3-layer, mean aggr, fp32. CSR built per-launch (ws is re-poisoned).
// Layers 1-2: agg(64) -> lin(relu). Layer 3: pre-transform to 40 dims, agg(40),
// self-path staged in d_out, log_softmax in place.

// ---------------- CSR build ----------------

__global__ void hist_kernel(const int* __restrict__ dstA, int* __restrict__ deg, int E) {
    int e = blockIdx.x * 256 + threadIdx.x;
    if (e < E) atomicAdd(&deg[dstA[e]], 1);
}

__global__ void scan_block_kernel(const int* __restrict__ deg, int* __restrict__ partial,
                                  int* __restrict__ bsum, int n) {
    __shared__ int sums[256];
    int t = threadIdx.x;
    int base = blockIdx.x * 1024 + t * 4;
    int v0 = 0, v1 = 0, v2 = 0, v3 = 0;
    if (base + 3 < n) {
        int4 q = *(const int4*)(deg + base);
        v0 = q.x; v1 = q.y; v2 = q.z; v3 = q.w;
    } else {
        if (base < n)     v0 = deg[base];
        if (base + 1 < n) v1 = deg[base + 1];
        if (base + 2 < n) v2 = deg[base + 2];
    }
    int s = v0 + v1 + v2 + v3;
    sums[t] = s;
    __syncthreads();
    for (int off = 1; off < 256; off <<= 1) {
        int x = 0;
        if (t >= off) x = sums[t - off];
        __syncthreads();
        sums[t] += x;
        __syncthreads();
    }
    int run = sums[t] - s;  // exclusive prefix within block
    if (base < n)     partial[base] = run;     run += v0;
    if (base + 1 < n) partial[base + 1] = run; run += v1;
    if (base + 2 < n) partial[base + 2] = run; run += v2;
    if (base + 3 < n) partial[base + 3] = run;
    if (t == 255) bsum[blockIdx.x] = sums[255];
}

__global__ void scan_sums_kernel(int* __restrict__ bsum, int nb) {
    __shared__ int s2[128];
    int t = threadIdx.x;
    int v = (t < nb) ? bsum[t] : 0;
    s2[t] = v;
    __syncthreads();
    for (int off = 1; off < 128; off <<= 1) {
        int x = 0;
        if (t >= off) x = s2[t - off];
        __syncthreads();
        s2[t] += x;
        __syncthreads();
    }
    if (t < nb) bsum[t] = s2[t] - v;  // exclusive block offsets
}

__global__ void finalize_kernel(const int* __restrict__ deg, int* __restrict__ row_start,
                                const int* __restrict__ bsum, int* __restrict__ cursor,
                                float* __restrict__ invd, int n) {
    int i = blockIdx.x * 256 + threadIdx.x;
    if (i >= n) return;
    int rs = row_start[i] + bsum[i >> 10];
    row_start[i] = rs;
    cursor[i] = rs;
    int d = deg[i];
    invd[i] = 1.0f / (float)(d > 0 ? d : 1);
}

__global__ void scatter_kernel(const int* __restrict__ srcA, const int* __restrict__ dstA,
                               int* __restrict__ cursor, int* __restrict__ col, int E) {
    int e = blockIdx.x * 256 + threadIdx.x;
    if (e < E) {
        int d = dstA[e];
        int pos = atomicAdd(&cursor[d], 1);
        col[pos] = srcA[e];
    }
}

// ---------------- mean aggregation (16-lane group per node) ----------------
// FV float4s per row are live (16 for F=64, 10 for F=40). For L3: OUT already
// holds the self-path r3; add it and write back in place.

template<int FV, int LDX, bool L3>
__global__ __launch_bounds__(256) void agg_kernel(const float* __restrict__ X,
                                                  const int* __restrict__ rs,
                                                  const int* __restrict__ degA,
                                                  const float* __restrict__ invd,
                                                  const int* __restrict__ col,
                                                  float* __restrict__ OUT, int n) {
    int t = threadIdx.x;
    int node = blockIdx.x * 16 + (t >> 4);
    if (node >= n) return;
    int lane = t & 15;
    int s = rs[node], d = degA[node];
    bool act = lane < FV;
    float ax = 0.f, ay = 0.f, az = 0.f, aw = 0.f;
    const float* lp = X + (size_t)lane * 4;
    int j = 0;
    for (; j + 1 < d; j += 2) {
        int c0 = col[s + j], c1 = col[s + j + 1];
        if (act) {
            float4 v0 = *(const float4*)(lp + (size_t)c0 * LDX);
            float4 v1 = *(const float4*)(lp + (size_t)c1 * LDX);
            ax += v0.x + v1.x; ay += v0.y + v1.y;
            az += v0.z + v1.z; aw += v0.w + v1.w;
        }
    }
    if (j < d) {
        int c0 = col[s + j];
        if (act) {
            float4 v0 = *(const float4*)(lp + (size_t)c0 * LDX);
            ax += v0.x; ay += v0.y; az += v0.z; aw += v0.w;
        }
    }
    float w = invd[node];
    ax *= w; ay *= w; az *= w; aw *= w;
    if (act) {
        float* op = OUT + (size_t)node * LDX + lane * 4;
        if (L3) {
            float4 r = *(const float4*)op;
            ax += r.x; ay += r.y; az += r.z; aw += r.w;
        }
        float4 o; o.x = ax; o.y = ay; o.z = az; o.w = aw;
        *(float4*)op = o;
    }
}

// ---------------- fused linear: OUT = relu(A@Wl^T + b + X@Wr^T) ----------------
// 32 rows/block; thread = (rowpair, colgroup of 4). In-place X==OUT is safe:
// block stages its own rows before writing them.

__global__ __launch_bounds__(256) void lin12_kernel(const float* __restrict__ X,
                                                    const float* __restrict__ A,
                                                    const float* __restrict__ Wl,
                                                    const float* __restrict__ Wr,
                                                    const float* __restrict__ bias,
                                                    float* __restrict__ OUT) {
    __shared__ float Wls[64][65];
    __shared__ float Wrs[64][65];
    __shared__ float Xs[32][65];
    __shared__ float As[32][65];
    int t = threadIdx.x;
    int rowbase = blockIdx.x * 32;
#pragma unroll
    for (int it = 0; it < 4; ++it) {
        int idx4 = it * 256 + t;          // 1024 float4 = 64x64
        int c = idx4 >> 4, kq = (idx4 & 15) * 4;
        float4 wl = ((const float4*)Wl)[idx4];
        float4 wr = ((const float4*)Wr)[idx4];
        Wls[c][kq] = wl.x; Wls[c][kq + 1] = wl.y; Wls[c][kq + 2] = wl.z; Wls[c][kq + 3] = wl.w;
        Wrs[c][kq] = wr.x; Wrs[c][kq + 1] = wr.y; Wrs[c][kq + 2] = wr.z; Wrs[c][kq + 3] = wr.w;
    }
#pragma unroll
    for (int it = 0; it < 2; ++it) {
        int idx4 = it * 256 + t;          // 512 float4 = 32 rows x 16
        int r = idx4 >> 4, kq = (idx4 & 15) * 4;
        float4 xv = ((const float4*)(X + (size_t)(rowbase + r) * 64))[idx4 & 15];
        float4 av = ((const float4*)(A + (size_t)(rowbase + r) * 64))[idx4 & 15];
        Xs[r][kq] = xv.x; Xs[r][kq + 1] = xv.y; Xs[r][kq + 2] = xv.z; Xs[r][kq + 3] = xv.w;
        As[r][kq] = av.x; As[r][kq + 1] = av.y; As[r][kq + 2] = av.z; As[r][kq + 3] = av.w;
    }
    __syncthreads();
    int rp = t >> 4, cg = t & 15;
    int r0 = rp * 2, r1 = r0 + 1, c0 = cg * 4;
    float4 acc0 = {0, 0, 0, 0}, acc1 = {0, 0, 0, 0};
#pragma unroll
    for (int k = 0; k < 64; ++k) {
        float a0 = As[r0][k], a1 = As[r1][k];
        float x0 = Xs[r0][k], x1 = Xs[r1][k];
        float wl0 = Wls[c0][k], wl1 = Wls[c0 + 1][k], wl2 = Wls[c0 + 2][k], wl3 = Wls[c0 + 3][k];
        float wr0 = Wrs[c0][k], wr1 = Wrs[c0 + 1][k], wr2 = Wrs[c0 + 2][k], wr3 = Wrs[c0 + 3][k];
        acc0.x = fmaf(a0, wl0, fmaf(x0, wr0, acc0.x));
        acc0.y = fmaf(a0, wl1, fmaf(x0, wr1, acc0.y));
        acc0.z = fmaf(a0, wl2, fmaf(x0, wr2, acc0.z));
        acc0.w = fmaf(a0, wl3, fmaf(x0, wr3, acc0.w));
        acc1.x = fmaf(a1, wl0, fmaf(x1, wr0, acc1.x));
        acc1.y = fmaf(a1, wl1, fmaf(x1, wr1, acc1.y));
        acc1.z = fmaf(a1, wl2, fmaf(x1, wr2, acc1.z));
        acc1.w = fmaf(a1, wl3, fmaf(x1, wr3, acc1.w));
    }
    float4 bb = ((const float4*)bias)[cg];
    acc0.x = fmaxf(acc0.x + bb.x, 0.f); acc0.y = fmaxf(acc0.y + bb.y, 0.f);
    acc0.z = fmaxf(acc0.z + bb.z, 0.f); acc0.w = fmaxf(acc0.w + bb.w, 0.f);
    acc1.x = fmaxf(acc1.x + bb.x, 0.f); acc1.y = fmaxf(acc1.y + bb.y, 0.f);
    acc1.z = fmaxf(acc1.z + bb.z, 0.f); acc1.w = fmaxf(acc1.w + bb.w, 0.f);
    ((float4*)(OUT + (size_t)(rowbase + r0) * 64))[cg] = acc0;
    ((float4*)(OUT + (size_t)(rowbase + r1) * 64))[cg] = acc1;
}

// ---------------- layer-3 pre-transform: Z = X@Wl3^T (N,40), R = X@Wr3^T + b3 ----------------
// 20 rows/block; 200 active threads: cg<10 -> Wl path (Z), cg>=10 -> Wr path + bias (R).

__global__ __launch_bounds__(256) void lin3_kernel(const float* __restrict__ X,
                                                   const float* __restrict__ Wl,
                                                   const float* __restrict__ Wr,
                                                   const float* __restrict__ bias,
                                                   float* __restrict__ Z,
                                                   float* __restrict__ R) {
    __shared__ float Ws[80][65];
    __shared__ float Xs[20][65];
    int t = threadIdx.x;
    int rowbase = blockIdx.x * 20;
#pragma unroll
    for (int it = 0; it < 5; ++it) {
        int idx4 = it * 256 + t;          // 1280 float4 = 80x64
        int c = idx4 >> 4, kq = (idx4 & 15) * 4;
        float4 w = (c < 40) ? ((const float4*)Wl)[idx4] : ((const float4*)Wr)[idx4 - 640];
        Ws[c][kq] = w.x; Ws[c][kq + 1] = w.y; Ws[c][kq + 2] = w.z; Ws[c][kq + 3] = w.w;
    }
#pragma unroll
    for (int it = 0; it < 2; ++it) {
        int idx4 = it * 256 + t;          // 320 float4 = 20 rows x 16
        if (idx4 < 320) {
            int r = idx4 >> 4, kq = (idx4 & 15) * 4;
            float4 xv = ((const float4*)(X + (size_t)(rowbase + r) * 64))[idx4 & 15];
            Xs[r][kq] = xv.x; Xs[r][kq + 1] = xv.y; Xs[r][kq + 2] = xv.z; Xs[r][kq + 3] = xv.w;
        }
    }
    __syncthreads();
    if (t >= 200) return;
    int rp = t / 20, cg = t % 20;
    int r0 = rp * 2, r1 = r0 + 1;
    bool lpath = cg < 10;
    int c0 = (lpath ? cg : cg - 10) * 4;
    int wc = lpath ? c0 : 40 + c0;
    float4 acc0 = {0, 0, 0, 0}, acc1 = {0, 0, 0, 0};
#pragma unroll
    for (int k = 0; k < 64; ++k) {
        float x0 = Xs[r0][k], x1 = Xs[r1][k];
        float w0 = Ws[wc][k], w1 = Ws[wc + 1][k], w2 = Ws[wc + 2][k], w3 = Ws[wc + 3][k];
        acc0.x = fmaf(x0, w0, acc0.x); acc0.y = fmaf(x0, w1, acc0.y);
        acc0.z = fmaf(x0, w2, acc0.z); acc0.w = fmaf(x0, w3, acc0.w);
        acc1.x = fmaf(x1, w0, acc1.x); acc1.y = fmaf(x1, w1, acc1.y);
        acc1.z = fmaf(x1, w2, acc1.z); acc1.w = fmaf(x1, w3, acc1.w);
    }
    if (!lpath) {
        float4 bb = ((const float4*)bias)[c0 >> 2];
        acc0.x += bb.x; acc0.y += bb.y; acc0.z += bb.z; acc0.w += bb.w;
        acc1.x += bb.x; acc1.y += bb.y; acc1.z += bb.z; acc1.w += bb.w;
    }
    float* dp = lpath ? Z : R;
    ((float4*)(dp + (size_t)(rowbase + r0) * 40))[c0 >> 2] = acc0;
    ((float4*)(dp + (size_t)(rowbase + r1) * 40))[c0 >> 2] = acc1;
}

// ---------------- log_softmax in place, one wave per node ----------------

__global__ __launch_bounds__(256) void lsm_kernel(float* __restrict__ out, int n) {
    int t = threadIdx.x;
    int node = blockIdx.x * 4 + (t >> 6);
    if (node >= n) return;
    int lane = t & 63;
    float v = (lane < 40) ? out[(size_t)node * 40 + lane] : -3.4e38f;
    float m = v;
#pragma unroll
    for (int off = 32; off > 0; off >>= 1) m = fmaxf(m, __shfl_xor(m, off));
    float e = (lane < 40) ? expf(v - m) : 0.f;
    float ssum = e;
#pragma unroll
    for (int off = 32; off > 0; off >>= 1) ssum += __shfl_xor(ssum, off);
    if (lane < 40) out[(size_t)node * 40 + lane] = v - m - logf(ssum);
}

// ---------------- launch ----------------

extern "C" void kernel_launch(void* const* d_in, const int* in_sizes, int n_in,
                              void* d_out, int out_size, void* d_ws, size_t ws_size,
                              hipStream_t stream) {
    const float* x   = (const float*)d_in[0];
    const int*   ei  = (const int*)d_in[1];
    const float* Wl1 = (const float*)d_in[2];
    const float* Wr1 = (const float*)d_in[3];
    const float* b1  = (const float*)d_in[4];
    const float* Wl2 = (const float*)d_in[5];
    const float* Wr2 = (const float*)d_in[6];
    const float* b2  = (const float*)d_in[7];
    const float* Wl3 = (const float*)d_in[8];
    const float* Wr3 = (const float*)d_in[9];
    const float* b3  = (const float*)d_in[10];
    float* out = (float*)d_out;

    const int N = in_sizes[0] / 64;
    const int E = in_sizes[1] / 2;
    const int* srcA = ei;
    const int* dstA = ei + E;

    char* ws = (char*)d_ws;
    size_t off = 0;
    auto alloc = [&](size_t bytes) {
        off = (off + 255) & ~(size_t)255;
        char* p = ws + off;
        off += bytes;
        return p;
    };
    int*   deg       = (int*)alloc((size_t)N * 4);
    int*   row_start = (int*)alloc((size_t)N * 4);
    int*   cursor    = (int*)alloc((size_t)N * 4);
    int*   bsum      = (int*)alloc(1024);
    int*   col       = (int*)alloc((size_t)E * 4);
    float* invd      = (float*)alloc((size_t)N * 4);
    float* AGG       = (float*)alloc((size_t)N * 64 * 4);
    float* Hb        = (float*)alloc((size_t)N * 64 * 4);

    // CSR build
    hipMemsetAsync(deg, 0, (size_t)N * 4, stream);
    hist_kernel<<<(E + 255) / 256, 256, 0, stream>>>(dstA, deg, E);
    int nb = (N + 1023) / 1024;
    scan_block_kernel<<<nb, 256, 0, stream>>>(deg, row_start, bsum, N);
    scan_sums_kernel<<<1, 128, 0, stream>>>(bsum, nb);
    finalize_kernel<<<(N + 255) / 256, 256, 0, stream>>>(deg, row_start, bsum, cursor, invd, N);
    scatter_kernel<<<(E + 255) / 256, 256, 0, stream>>>(srcA, dstA, cursor, col, E);

    // layer 1: h1 = relu(mean(x)@Wl1^T + b1 + x@Wr1^T)
    agg_kernel<16, 64, false><<<(N + 15) / 16, 256, 0, stream>>>(x, row_start, deg, invd, col, AGG, N);
    lin12_kernel<<<N / 32, 256, 0, stream>>>(x, AGG, Wl1, Wr1, b1, Hb);

    // layer 2 (in-place on Hb)
    agg_kernel<16, 64, false><<<(N + 15) / 16, 256, 0, stream>>>(Hb, row_start, deg, invd, col, AGG, N);
    lin12_kernel<<<N / 32, 256, 0, stream>>>(Hb, AGG, Wl2, Wr2, b2, Hb);

    // layer 3: pre-transform (agg is linear): Z = h2@Wl3^T (N,40) in AGG buf, R = h2@Wr3^T+b3 in d_out
    lin3_kernel<<<N / 20, 256, 0, stream>>>(Hb, Wl3, Wr3, b3, AGG, out);
    agg_kernel<10, 40, true><<<(N + 15) / 16, 256, 0, stream>>>(AGG, row_start, deg, invd, col, out, N);

    // log_softmax in place
    lsm_kernel<<<(N + 3) / 4, 256, 0, stream>>>(out, N);
}